// Round 1
// baseline (19088.414 us; speedup 1.0000x reference)
//
#include <hip/hip_runtime.h>
#include <hip/hip_cooperative_groups.h>

namespace cg = cooperative_groups;

// Problem constants
#define BB   64      // batch
#define TT   256     // seq len
#define II   768     // input dim
#define HH   384     // hidden per direction
#define DD   768     // 2*HH
#define G3   1152    // 3*HH
#define G6   2304    // both directions' gates

#define TILE 128
#define BK   16

// ---------------------------------------------------------------------------
// GEMM: gx[t][b][n] = bias[n] + sum_k X[t,b,k] * W[n,k]   (n in [0,2304))
// n < 1152 -> forward weights, else backward. K = 768 for both layers.
// xmode 0: X = Sentences [B][T][768]; xmode 1: X = [T*B][768] row-major.
// ---------------------------------------------------------------------------
__global__ __launch_bounds__(256) void gemm_gx(
    const float* __restrict__ X, int xmode,
    const float* __restrict__ wf, const float* __restrict__ wb,
    const float* __restrict__ bif, const float* __restrict__ bib,
    float* __restrict__ gx)
{
    __shared__ float As[BK][TILE + 4];
    __shared__ float Bs[BK][TILE + 4];
    const int tid = threadIdx.x;
    const int tx = tid & 15, ty = tid >> 4;
    const int m0 = blockIdx.y * TILE;
    const int n0 = blockIdx.x * TILE;

    float acc[8][8];
#pragma unroll
    for (int i = 0; i < 8; i++)
#pragma unroll
        for (int j = 0; j < 8; j++) acc[i][j] = 0.f;

    for (int k0 = 0; k0 < 768; k0 += BK) {
#pragma unroll
        for (int l = 0; l < 2; l++) {
            int id = tid + l * 256;          // 0..511
            int r  = id >> 2;                // 0..127
            int kq = (id & 3) * 4;
            int m  = m0 + r;
            const float* src;
            if (xmode == 0) {
                int b = m & 63, t = m >> 6;
                src = X + (size_t)b * (TT * II) + (size_t)t * II + k0 + kq;
            } else {
                src = X + (size_t)m * 768 + k0 + kq;
            }
            float4 v = *(const float4*)src;
            As[kq + 0][r] = v.x; As[kq + 1][r] = v.y;
            As[kq + 2][r] = v.z; As[kq + 3][r] = v.w;
        }
#pragma unroll
        for (int l = 0; l < 2; l++) {
            int id = tid + l * 256;
            int r  = id >> 2;
            int kq = (id & 3) * 4;
            int n  = n0 + r;
            const float* wsrc = (n < G3) ? (wf + (size_t)n * 768)
                                         : (wb + (size_t)(n - G3) * 768);
            float4 v = *(const float4*)(wsrc + k0 + kq);
            Bs[kq + 0][r] = v.x; Bs[kq + 1][r] = v.y;
            Bs[kq + 2][r] = v.z; Bs[kq + 3][r] = v.w;
        }
        __syncthreads();
#pragma unroll
        for (int kk = 0; kk < BK; ++kk) {
            float av[8], bv[8];
            *(float4*)&av[0] = *(const float4*)&As[kk][ty * 8];
            *(float4*)&av[4] = *(const float4*)&As[kk][ty * 8 + 4];
            *(float4*)&bv[0] = *(const float4*)&Bs[kk][tx * 8];
            *(float4*)&bv[4] = *(const float4*)&Bs[kk][tx * 8 + 4];
#pragma unroll
            for (int i = 0; i < 8; i++)
#pragma unroll
                for (int j = 0; j < 8; j++)
                    acc[i][j] = fmaf(av[i], bv[j], acc[i][j]);
        }
        __syncthreads();
    }

#pragma unroll
    for (int i = 0; i < 8; i++) {
        int m = m0 + ty * 8 + i;
        int t = m >> 6, b = m & 63;
        float* dst = gx + (size_t)t * (BB * G6) + (size_t)b * G6 + n0 + tx * 8;
#pragma unroll
        for (int j = 0; j < 8; j++) {
            int n = n0 + tx * 8 + j;
            float bias = (n < G3) ? bif[n] : bib[n - G3];
            dst[j] = acc[i][j] + bias;
        }
    }
}

// ---------------------------------------------------------------------------
// Cooperative recurrent kernel: one layer, both directions.
// Grid = 192 WGs x 256 threads. WGs 0..95 forward, 96..191 backward.
// Each WG owns 4 hidden columns (c0..c0+3); wave j owns column c0+j;
// lane = batch. h ping-pong in global; grid.sync() per timestep.
// ---------------------------------------------------------------------------
__global__ __launch_bounds__(256) void recur(
    const float* __restrict__ gx,   // [T][B][2304] (b_ih already added)
    const float* __restrict__ whf, const float* __restrict__ whb,
    const float* __restrict__ bhf, const float* __restrict__ bhb,
    float* __restrict__ hbuf,       // [2 dir][2 pp][64*384], pre-zeroed
    float* __restrict__ out)        // [T][B][768]
{
    cg::grid_group grid = cg::this_grid();
    const int wg   = blockIdx.x;          // 0..191
    const int dir  = wg / 96;
    const int c0   = (wg % 96) * 4;
    const int tid  = threadIdx.x;
    const int lane = tid & 63;            // batch
    const int j    = __builtin_amdgcn_readfirstlane(tid >> 6);  // wave 0..3
    const int col  = c0 + j;              // this wave's hidden column

    const float* wh = dir ? whb : whf;
    const float* bh = dir ? bhb : bhf;
    const float* wr = wh + (size_t)(0 * HH + col) * HH;
    const float* wz = wh + (size_t)(1 * HH + col) * HH;
    const float* wn = wh + (size_t)(2 * HH + col) * HH;
    const float bhr = bh[col], bhz = bh[HH + col], bhn = bh[2 * HH + col];

    __shared__ float hs[64][196];         // half-K staging (192 + pad 4)

    float* h0 = hbuf + (size_t)dir * 2 * (BB * HH);

    for (int s = 0; s < TT; s++) {
        const int t = dir ? (TT - 1 - s) : s;
        const float* hcur = h0 + (size_t)(s & 1) * (BB * HH);
        float*       hnxt = h0 + (size_t)((s & 1) ^ 1) * (BB * HH);

        float accr = 0.f, accz = 0.f, accn = 0.f;
#pragma unroll
        for (int half = 0; half < 2; half++) {
            const int kbase = half * 192;
            // stage 64 x 192 floats (3072 float4, 12 per thread)
#pragma unroll
            for (int l = 0; l < 12; l++) {
                int id = tid + l * 256;            // 0..3071
                int bb = id / 48;                  // row (batch)
                int kq = (id % 48) * 4;            // col within half
                float4 v = *(const float4*)(hcur + (size_t)bb * HH + kbase + kq);
                *(float4*)(&hs[bb][kq]) = v;
            }
            __syncthreads();
#pragma unroll 8
            for (int kc = 0; kc < 48; kc++) {
                float4 hv = *(const float4*)(&hs[lane][kc * 4]);
                float4 w1 = *(const float4*)(wr + kbase + kc * 4);  // uniform -> s_load
                float4 w2 = *(const float4*)(wz + kbase + kc * 4);
                float4 w3 = *(const float4*)(wn + kbase + kc * 4);
                accr = fmaf(hv.x, w1.x, accr); accr = fmaf(hv.y, w1.y, accr);
                accr = fmaf(hv.z, w1.z, accr); accr = fmaf(hv.w, w1.w, accr);
                accz = fmaf(hv.x, w2.x, accz); accz = fmaf(hv.y, w2.y, accz);
                accz = fmaf(hv.z, w2.z, accz); accz = fmaf(hv.w, w2.w, accz);
                accn = fmaf(hv.x, w3.x, accn); accn = fmaf(hv.y, w3.y, accn);
                accn = fmaf(hv.z, w3.z, accn); accn = fmaf(hv.w, w3.w, accn);
            }
            __syncthreads();   // hs reused by next half / next step
        }

        // gate math (wave-local)
        const float* gxp = gx + (size_t)t * (BB * G6) + (size_t)lane * G6 + dir * G3;
        float gr = gxp[col], gz = gxp[HH + col], gn = gxp[2 * HH + col];
        float ghr = accr + bhr, ghz = accz + bhz, ghn = accn + bhn;
        float r  = 1.f / (1.f + expf(-(gr + ghr)));
        float z  = 1.f / (1.f + expf(-(gz + ghz)));
        float nn = tanhf(gn + r * ghn);
        float hprev = hcur[(size_t)lane * HH + col];
        float hnew  = (1.f - z) * nn + z * hprev;

        hnxt[(size_t)lane * HH + col] = hnew;
        out[(size_t)t * (BB * DD) + (size_t)lane * DD + dir * HH + col] = hnew;

        grid.sync();
    }
}

// ---------------------------------------------------------------------------
// Attention logits: logits[b][t] += sum_n tanh(hidden[t,b,:]·fcw[n,:] + fcb[n]) * upw[n]
// Same 128x128 tiling; atomicAdd across the 6 n-tiles. logits pre-zeroed.
// ---------------------------------------------------------------------------
__global__ __launch_bounds__(256) void attn_logits(
    const float* __restrict__ Xh,   // hidden [T*B][768]
    const float* __restrict__ fcw,  // [768][768]
    const float* __restrict__ fcb, const float* __restrict__ upw,
    float* __restrict__ logits)     // [B][T]
{
    __shared__ float As[BK][TILE + 4];
    __shared__ float Bs[BK][TILE + 4];
    __shared__ float red[TILE][17];
    const int tid = threadIdx.x;
    const int tx = tid & 15, ty = tid >> 4;
    const int m0 = blockIdx.y * TILE;
    const int n0 = blockIdx.x * TILE;

    float acc[8][8];
#pragma unroll
    for (int i = 0; i < 8; i++)
#pragma unroll
        for (int j = 0; j < 8; j++) acc[i][j] = 0.f;

    for (int k0 = 0; k0 < 768; k0 += BK) {
#pragma unroll
        for (int l = 0; l < 2; l++) {
            int id = tid + l * 256;
            int r  = id >> 2;
            int kq = (id & 3) * 4;
            float4 v = *(const float4*)(Xh + (size_t)(m0 + r) * 768 + k0 + kq);
            As[kq + 0][r] = v.x; As[kq + 1][r] = v.y;
            As[kq + 2][r] = v.z; As[kq + 3][r] = v.w;
        }
#pragma unroll
        for (int l = 0; l < 2; l++) {
            int id = tid + l * 256;
            int r  = id >> 2;
            int kq = (id & 3) * 4;
            float4 v = *(const float4*)(fcw + (size_t)(n0 + r) * 768 + k0 + kq);
            Bs[kq + 0][r] = v.x; Bs[kq + 1][r] = v.y;
            Bs[kq + 2][r] = v.z; Bs[kq + 3][r] = v.w;
        }
        __syncthreads();
#pragma unroll
        for (int kk = 0; kk < BK; ++kk) {
            float av[8], bv[8];
            *(float4*)&av[0] = *(const float4*)&As[kk][ty * 8];
            *(float4*)&av[4] = *(const float4*)&As[kk][ty * 8 + 4];
            *(float4*)&bv[0] = *(const float4*)&Bs[kk][tx * 8];
            *(float4*)&bv[4] = *(const float4*)&Bs[kk][tx * 8 + 4];
#pragma unroll
            for (int i = 0; i < 8; i++)
#pragma unroll
                for (int j = 0; j < 8; j++)
                    acc[i][j] = fmaf(av[i], bv[j], acc[i][j]);
        }
        __syncthreads();
    }

#pragma unroll
    for (int i = 0; i < 8; i++) {
        float p = 0.f;
#pragma unroll
        for (int jj = 0; jj < 8; jj++) {
            int n = n0 + tx * 8 + jj;
            p += tanhf(acc[i][jj] + fcb[n]) * upw[n];
        }
        red[ty * 8 + i][tx] = p;
    }
    __syncthreads();
    if (tid < TILE) {
        float s = 0.f;
#pragma unroll
        for (int x = 0; x < 16; x++) s += red[tid][x];
        int m = m0 + tid;
        int t = m >> 6, b = m & 63;
        atomicAdd(&logits[(size_t)b * TT + t], s);
    }
}

// ---------------------------------------------------------------------------
// Softmax over T per batch + weighted pooling: out[b][d] = sum_t alpha*hidden
// ---------------------------------------------------------------------------
__global__ __launch_bounds__(256) void softmax_pool(
    const float* __restrict__ logits, const float* __restrict__ upwb,
    const float* __restrict__ hidden, float* __restrict__ out)
{
    const int b = blockIdx.x, tid = threadIdx.x;
    __shared__ float sa[256];
    __shared__ float red[256];

    float l = logits[(size_t)b * TT + tid] + upwb[0];
    red[tid] = l; __syncthreads();
    for (int s = 128; s > 0; s >>= 1) {
        if (tid < s) red[tid] = fmaxf(red[tid], red[tid + s]);
        __syncthreads();
    }
    float mx = red[0];
    __syncthreads();
    float e = expf(l - mx);
    sa[tid] = e; red[tid] = e; __syncthreads();
    for (int s = 128; s > 0; s >>= 1) {
        if (tid < s) red[tid] += red[tid + s];
        __syncthreads();
    }
    float inv = 1.f / red[0];

    float o0 = 0.f, o1 = 0.f, o2 = 0.f;
    for (int t = 0; t < TT; t++) {
        float a = sa[t] * inv;
        const float* hp = hidden + (size_t)t * (BB * DD) + (size_t)b * DD;
        o0 = fmaf(a, hp[tid],       o0);
        o1 = fmaf(a, hp[tid + 256], o1);
        o2 = fmaf(a, hp[tid + 512], o2);
    }
    out[(size_t)b * DD + tid]       = o0;
    out[(size_t)b * DD + tid + 256] = o1;
    out[(size_t)b * DD + tid + 512] = o2;
}

// ---------------------------------------------------------------------------
extern "C" void kernel_launch(void* const* d_in, const int* in_sizes, int n_in,
                              void* d_out, int out_size, void* d_ws, size_t ws_size,
                              hipStream_t stream)
{
    const float* S        = (const float*)d_in[0];
    const float* w_ih_l0f = (const float*)d_in[1];
    const float* w_hh_l0f = (const float*)d_in[2];
    const float* b_ih_l0f = (const float*)d_in[3];
    const float* b_hh_l0f = (const float*)d_in[4];
    const float* w_ih_l0b = (const float*)d_in[5];
    const float* w_hh_l0b = (const float*)d_in[6];
    const float* b_ih_l0b = (const float*)d_in[7];
    const float* b_hh_l0b = (const float*)d_in[8];
    const float* w_ih_l1f = (const float*)d_in[9];
    const float* w_hh_l1f = (const float*)d_in[10];
    const float* b_ih_l1f = (const float*)d_in[11];
    const float* b_hh_l1f = (const float*)d_in[12];
    const float* w_ih_l1b = (const float*)d_in[13];
    const float* w_hh_l1b = (const float*)d_in[14];
    const float* b_ih_l1b = (const float*)d_in[15];
    const float* b_hh_l1b = (const float*)d_in[16];
    const float* fc_w     = (const float*)d_in[17];
    const float* fc_b     = (const float*)d_in[18];
    const float* upw_w    = (const float*)d_in[19];
    const float* upw_b    = (const float*)d_in[20];

    // workspace layout (floats)
    float* gxb    = (float*)d_ws;                       // 256*64*2304 = 37,748,736
    float* buf2   = gxb  + (size_t)TT * BB * G6;        // 256*64*768  = 12,582,912
    float* hbuf   = buf2 + (size_t)TT * BB * DD;        // 2*2*64*384  = 98,304
    float* logits = hbuf + (size_t)2 * 2 * BB * HH;     // 64*256      = 16,384

    // zero h ping-pong + logits (contiguous)
    hipMemsetAsync(hbuf, 0, (size_t)(2 * 2 * BB * HH + BB * TT) * sizeof(float), stream);

    // layer 0 input gates
    gemm_gx<<<dim3(18, 128), 256, 0, stream>>>(S, 0, w_ih_l0f, w_ih_l0b,
                                               b_ih_l0f, b_ih_l0b, gxb);
    // layer 0 recurrence -> buf2
    {
        void* args[] = {(void*)&gxb, (void*)&w_hh_l0f, (void*)&w_hh_l0b,
                        (void*)&b_hh_l0f, (void*)&b_hh_l0b, (void*)&hbuf, (void*)&buf2};
        hipLaunchCooperativeKernel((const void*)recur, dim3(192), dim3(256),
                                   args, 0, stream);
    }
    // re-zero h for layer 1
    hipMemsetAsync(hbuf, 0, (size_t)(2 * 2 * BB * HH) * sizeof(float), stream);

    // layer 1 input gates (from buf2)
    gemm_gx<<<dim3(18, 128), 256, 0, stream>>>(buf2, 1, w_ih_l1f, w_ih_l1b,
                                               b_ih_l1f, b_ih_l1b, gxb);
    // layer 1 recurrence -> buf2 (overwrites; gx already materialized)
    {
        void* args[] = {(void*)&gxb, (void*)&w_hh_l1f, (void*)&w_hh_l1b,
                        (void*)&b_hh_l1f, (void*)&b_hh_l1b, (void*)&hbuf, (void*)&buf2};
        hipLaunchCooperativeKernel((const void*)recur, dim3(192), dim3(256),
                                   args, 0, stream);
    }
    // attention logits + pooling
    attn_logits<<<dim3(6, 128), 256, 0, stream>>>(buf2, fc_w, fc_b, upw_w, logits);
    softmax_pool<<<64, 256, 0, stream>>>(logits, upw_b, buf2, (float*)d_out);
}

// Round 2
// 13886.682 us; speedup vs baseline: 1.3746x; 1.3746x over previous
//
#include <hip/hip_runtime.h>

// Problem constants
#define BB   64      // batch
#define TT   256     // seq len
#define II   768     // input dim
#define HH   384     // hidden per direction
#define DD   768     // 2*HH
#define G3   1152    // 3*HH
#define G6   2304    // both directions' gates

#define TILE 128
#define BK   16

typedef unsigned long long u64t;

// ---------------------------------------------------------------------------
// GEMM: gx[t][b][n] = bias[n] + sum_k X[t,b,k] * W[n,k]   (n in [0,2304))
// n < 1152 -> forward weights, else backward. K = 768 for both layers.
// xmode 0: X = Sentences [B][T][768]; xmode 1: X = [T*B][768] row-major.
// ---------------------------------------------------------------------------
__global__ __launch_bounds__(256) void gemm_gx(
    const float* __restrict__ X, int xmode,
    const float* __restrict__ wf, const float* __restrict__ wb,
    const float* __restrict__ bif, const float* __restrict__ bib,
    float* __restrict__ gx)
{
    __shared__ float As[BK][TILE + 4];
    __shared__ float Bs[BK][TILE + 4];
    const int tid = threadIdx.x;
    const int tx = tid & 15, ty = tid >> 4;
    const int m0 = blockIdx.y * TILE;
    const int n0 = blockIdx.x * TILE;

    float acc[8][8];
#pragma unroll
    for (int i = 0; i < 8; i++)
#pragma unroll
        for (int j = 0; j < 8; j++) acc[i][j] = 0.f;

    for (int k0 = 0; k0 < 768; k0 += BK) {
#pragma unroll
        for (int l = 0; l < 2; l++) {
            int id = tid + l * 256;          // 0..511
            int r  = id >> 2;                // 0..127
            int kq = (id & 3) * 4;
            int m  = m0 + r;
            const float* src;
            if (xmode == 0) {
                int b = m & 63, t = m >> 6;
                src = X + (size_t)b * (TT * II) + (size_t)t * II + k0 + kq;
            } else {
                src = X + (size_t)m * 768 + k0 + kq;
            }
            float4 v = *(const float4*)src;
            As[kq + 0][r] = v.x; As[kq + 1][r] = v.y;
            As[kq + 2][r] = v.z; As[kq + 3][r] = v.w;
        }
#pragma unroll
        for (int l = 0; l < 2; l++) {
            int id = tid + l * 256;
            int r  = id >> 2;
            int kq = (id & 3) * 4;
            int n  = n0 + r;
            const float* wsrc = (n < G3) ? (wf + (size_t)n * 768)
                                         : (wb + (size_t)(n - G3) * 768);
            float4 v = *(const float4*)(wsrc + k0 + kq);
            Bs[kq + 0][r] = v.x; Bs[kq + 1][r] = v.y;
            Bs[kq + 2][r] = v.z; Bs[kq + 3][r] = v.w;
        }
        __syncthreads();
#pragma unroll
        for (int kk = 0; kk < BK; ++kk) {
            float av[8], bv[8];
            *(float4*)&av[0] = *(const float4*)&As[kk][ty * 8];
            *(float4*)&av[4] = *(const float4*)&As[kk][ty * 8 + 4];
            *(float4*)&bv[0] = *(const float4*)&Bs[kk][tx * 8];
            *(float4*)&bv[4] = *(const float4*)&Bs[kk][tx * 8 + 4];
#pragma unroll
            for (int i = 0; i < 8; i++)
#pragma unroll
                for (int j = 0; j < 8; j++)
                    acc[i][j] = fmaf(av[i], bv[j], acc[i][j]);
        }
        __syncthreads();
    }

#pragma unroll
    for (int i = 0; i < 8; i++) {
        int m = m0 + ty * 8 + i;
        int t = m >> 6, b = m & 63;
        float* dst = gx + (size_t)t * (BB * G6) + (size_t)b * G6 + n0 + tx * 8;
#pragma unroll
        for (int j = 0; j < 8; j++) {
            int n = n0 + tx * 8 + j;
            float bias = (n < G3) ? bif[n] : bib[n - G3];
            dst[j] = acc[i][j] + bias;
        }
    }
}

// ---------------------------------------------------------------------------
// Recurrent kernel v2: one layer, both directions, cooperative launch but
// with a HAND-ROLLED flush-free barrier (grid.sync's device fence was
// writeback-invalidating L2 every step -> 795 MB of weight re-fetch).
//
// Grid = 192 WGs x 256 threads. WGs 0..95 forward, 96..191 backward.
// Wave j of WG owns hidden column c = (wg%96)*4 + j; lane = batch.
//
// h ping-pong lives in global memory in interleaved layout [k/4][b][4]
// (so staging is a straight linear copy and ds_read_b128 per (kc,lane) is a
// contiguous 1 KiB wave access = conflict-free). h is exchanged via
// agent-scope relaxed atomics (L2-bypassing, L3-coherent) so the barrier
// needs NO cache flush; weights/gx stay warm in L2 across all 256 steps.
// ---------------------------------------------------------------------------
__global__ __launch_bounds__(256) void recur2(
    const float* __restrict__ gx,   // [T][B][2304] (b_ih already added)
    const float* __restrict__ whf, const float* __restrict__ whb,
    const float* __restrict__ bhf, const float* __restrict__ bhb,
    float* __restrict__ hbuf,       // [2 dir][2 pp][96][64][4] floats, zeroed
    float* __restrict__ out,        // [T][B][768]
    unsigned* __restrict__ bar)     // [2] counters, zeroed
{
    const int wg   = blockIdx.x;          // 0..191
    const int dir  = wg / 96;
    const int tid  = threadIdx.x;
    const int lane = tid & 63;            // batch
    const int j    = __builtin_amdgcn_readfirstlane(tid >> 6);  // wave 0..3
    const int c    = (wg % 96) * 4 + j;   // this wave's hidden column

    const float* wh = dir ? whb : whf;
    const float* bh = dir ? bhb : bhf;
    const float4* wr = (const float4*)(wh + (size_t)(0 * HH + c) * HH);
    const float4* wz = (const float4*)(wh + (size_t)(1 * HH + c) * HH);
    const float4* wn = (const float4*)(wh + (size_t)(2 * HH + c) * HH);
    const float bhr = bh[c], bhz = bh[HH + c], bhn = bh[2 * HH + c];

    const int myc4 = c >> 2;              // my column's float4 group
    const int msub = c & 3;
    const int mh   = myc4 / 48;           // which staging half holds my col
    const int mrow = myc4 - mh * 48;

    __shared__ __align__(16) float hs[48 * 64 * 4];   // 49152 B (half of h)

    float* hpp = hbuf + (size_t)dir * 2 * (96 * 64 * 4);
    unsigned* cnt = bar + dir;

    for (int s = 0; s < TT; s++) {
        const int t = dir ? (TT - 1 - s) : s;
        const float* hcur = hpp + (size_t)(s & 1) * (96 * 64 * 4);
        float*       hnxt = hpp + (size_t)((s & 1) ^ 1) * (96 * 64 * 4);

        // prefetch gx for this step (normal L2 path, hides under staging)
        const float* gxp = gx + (size_t)t * (BB * G6) + (size_t)lane * G6 + dir * G3;
        float gr = gxp[c], gz = gxp[HH + c], gn = gxp[2 * HH + c];

        float accr = 0.f, accz = 0.f, accn = 0.f;
        float hprev = 0.f;

#pragma unroll
        for (int hh = 0; hh < 2; hh++) {
            // stage half of h: 12288 floats = 6144 u64, 24 per thread,
            // agent-scope relaxed loads (L2-bypass, read L3-coherent data)
            const u64t* src = (const u64t*)(hcur + hh * 12288);
            u64t* dst = (u64t*)hs;
#pragma unroll
            for (int l = 0; l < 24; l++) {
                u64t v = __hip_atomic_load((u64t*)(src + tid + l * 256),
                                           __ATOMIC_RELAXED, __HIP_MEMORY_SCOPE_AGENT);
                dst[tid + l * 256] = v;
            }
            __syncthreads();

            if (hh == mh)
                hprev = hs[(mrow * 64 + lane) * 4 + msub];

            const float4* wrb = wr + hh * 48;
            const float4* wzb = wz + hh * 48;
            const float4* wnb = wn + hh * 48;
#pragma unroll 8
            for (int kc = 0; kc < 48; kc++) {
                float4 hv = *(const float4*)(hs + (kc * 64 + lane) * 4);
                float4 w1 = wrb[kc];     // wave-uniform -> s_load, L2-warm
                float4 w2 = wzb[kc];
                float4 w3 = wnb[kc];
                accr = fmaf(hv.x, w1.x, accr); accr = fmaf(hv.y, w1.y, accr);
                accr = fmaf(hv.z, w1.z, accr); accr = fmaf(hv.w, w1.w, accr);
                accz = fmaf(hv.x, w2.x, accz); accz = fmaf(hv.y, w2.y, accz);
                accz = fmaf(hv.z, w2.z, accz); accz = fmaf(hv.w, w2.w, accz);
                accn = fmaf(hv.x, w3.x, accn); accn = fmaf(hv.y, w3.y, accn);
                accn = fmaf(hv.z, w3.z, accn); accn = fmaf(hv.w, w3.w, accn);
            }
            __syncthreads();   // hs reused by next half / next step
        }

        // gate math (wave-local, fp32)
        float ghr = accr + bhr, ghz = accz + bhz, ghn = accn + bhn;
        float r  = 1.f / (1.f + expf(-(gr + ghr)));
        float z  = 1.f / (1.f + expf(-(gz + ghz)));
        float nn = tanhf(gn + r * ghn);
        float hnew  = (1.f - z) * nn + z * hprev;

        // publish h_new at agent scope (L3-visible, no L2 flush needed)
        __hip_atomic_store(hnxt + (myc4 * 64 + lane) * 4 + msub, hnew,
                           __ATOMIC_RELAXED, __HIP_MEMORY_SCOPE_AGENT);
        // normal store for the big output tensor (flushed at kernel end)
        out[(size_t)t * (BB * DD) + (size_t)lane * DD + dir * HH + c] = hnew;

        if (s < TT - 1) {
            // flush-free barrier: __syncthreads drains vmcnt (so the h store
            // is committed), then one lane per WG arrives and spins.
            __syncthreads();
            if (tid == 0) {
                __hip_atomic_fetch_add(cnt, 1u, __ATOMIC_RELAXED,
                                       __HIP_MEMORY_SCOPE_AGENT);
                const unsigned tgt = 96u * (unsigned)(s + 1);
                while (__hip_atomic_load(cnt, __ATOMIC_RELAXED,
                                         __HIP_MEMORY_SCOPE_AGENT) < tgt)
                    __builtin_amdgcn_s_sleep(2);
            }
            __syncthreads();
        }
    }
}

// ---------------------------------------------------------------------------
// Attention logits: logits[b][t] += sum_n tanh(hidden[t,b,:]·fcw[n,:] + fcb[n]) * upw[n]
// ---------------------------------------------------------------------------
__global__ __launch_bounds__(256) void attn_logits(
    const float* __restrict__ Xh,   // hidden [T*B][768]
    const float* __restrict__ fcw,  // [768][768]
    const float* __restrict__ fcb, const float* __restrict__ upw,
    float* __restrict__ logits)     // [B][T]
{
    __shared__ float As[BK][TILE + 4];
    __shared__ float Bs[BK][TILE + 4];
    __shared__ float red[TILE][17];
    const int tid = threadIdx.x;
    const int tx = tid & 15, ty = tid >> 4;
    const int m0 = blockIdx.y * TILE;
    const int n0 = blockIdx.x * TILE;

    float acc[8][8];
#pragma unroll
    for (int i = 0; i < 8; i++)
#pragma unroll
        for (int j = 0; j < 8; j++) acc[i][j] = 0.f;

    for (int k0 = 0; k0 < 768; k0 += BK) {
#pragma unroll
        for (int l = 0; l < 2; l++) {
            int id = tid + l * 256;
            int r  = id >> 2;
            int kq = (id & 3) * 4;
            float4 v = *(const float4*)(Xh + (size_t)(m0 + r) * 768 + k0 + kq);
            As[kq + 0][r] = v.x; As[kq + 1][r] = v.y;
            As[kq + 2][r] = v.z; As[kq + 3][r] = v.w;
        }
#pragma unroll
        for (int l = 0; l < 2; l++) {
            int id = tid + l * 256;
            int r  = id >> 2;
            int kq = (id & 3) * 4;
            float4 v = *(const float4*)(fcw + (size_t)(n0 + r) * 768 + k0 + kq);
            Bs[kq + 0][r] = v.x; Bs[kq + 1][r] = v.y;
            Bs[kq + 2][r] = v.z; Bs[kq + 3][r] = v.w;
        }
        __syncthreads();
#pragma unroll
        for (int kk = 0; kk < BK; ++kk) {
            float av[8], bv[8];
            *(float4*)&av[0] = *(const float4*)&As[kk][ty * 8];
            *(float4*)&av[4] = *(const float4*)&As[kk][ty * 8 + 4];
            *(float4*)&bv[0] = *(const float4*)&Bs[kk][tx * 8];
            *(float4*)&bv[4] = *(const float4*)&Bs[kk][tx * 8 + 4];
#pragma unroll
            for (int i = 0; i < 8; i++)
#pragma unroll
                for (int j = 0; j < 8; j++)
                    acc[i][j] = fmaf(av[i], bv[j], acc[i][j]);
        }
        __syncthreads();
    }

#pragma unroll
    for (int i = 0; i < 8; i++) {
        float p = 0.f;
#pragma unroll
        for (int jj = 0; jj < 8; jj++) {
            int n = n0 + tx * 8 + jj;
            p += tanhf(acc[i][jj] + fcb[n]) * upw[n];
        }
        red[ty * 8 + i][tx] = p;
    }
    __syncthreads();
    if (tid < TILE) {
        float s = 0.f;
#pragma unroll
        for (int x = 0; x < 16; x++) s += red[tid][x];
        int m = m0 + tid;
        int t = m >> 6, b = m & 63;
        atomicAdd(&logits[(size_t)b * TT + t], s);
    }
}

// ---------------------------------------------------------------------------
// Softmax over T per batch + weighted pooling
// ---------------------------------------------------------------------------
__global__ __launch_bounds__(256) void softmax_pool(
    const float* __restrict__ logits, const float* __restrict__ upwb,
    const float* __restrict__ hidden, float* __restrict__ out)
{
    const int b = blockIdx.x, tid = threadIdx.x;
    __shared__ float sa[256];
    __shared__ float red[256];

    float l = logits[(size_t)b * TT + tid] + upwb[0];
    red[tid] = l; __syncthreads();
    for (int s = 128; s > 0; s >>= 1) {
        if (tid < s) red[tid] = fmaxf(red[tid], red[tid + s]);
        __syncthreads();
    }
    float mx = red[0];
    __syncthreads();
    float e = expf(l - mx);
    sa[tid] = e; red[tid] = e; __syncthreads();
    for (int s = 128; s > 0; s >>= 1) {
        if (tid < s) red[tid] += red[tid + s];
        __syncthreads();
    }
    float inv = 1.f / red[0];

    float o0 = 0.f, o1 = 0.f, o2 = 0.f;
    for (int t = 0; t < TT; t++) {
        float a = sa[t] * inv;
        const float* hp = hidden + (size_t)t * (BB * DD) + (size_t)b * DD;
        o0 = fmaf(a, hp[tid],       o0);
        o1 = fmaf(a, hp[tid + 256], o1);
        o2 = fmaf(a, hp[tid + 512], o2);
    }
    out[(size_t)b * DD + tid]       = o0;
    out[(size_t)b * DD + tid + 256] = o1;
    out[(size_t)b * DD + tid + 512] = o2;
}

// ---------------------------------------------------------------------------
extern "C" void kernel_launch(void* const* d_in, const int* in_sizes, int n_in,
                              void* d_out, int out_size, void* d_ws, size_t ws_size,
                              hipStream_t stream)
{
    const float* S        = (const float*)d_in[0];
    const float* w_ih_l0f = (const float*)d_in[1];
    const float* w_hh_l0f = (const float*)d_in[2];
    const float* b_ih_l0f = (const float*)d_in[3];
    const float* b_hh_l0f = (const float*)d_in[4];
    const float* w_ih_l0b = (const float*)d_in[5];
    const float* w_hh_l0b = (const float*)d_in[6];
    const float* b_ih_l0b = (const float*)d_in[7];
    const float* b_hh_l0b = (const float*)d_in[8];
    const float* w_ih_l1f = (const float*)d_in[9];
    const float* w_hh_l1f = (const float*)d_in[10];
    const float* b_ih_l1f = (const float*)d_in[11];
    const float* b_hh_l1f = (const float*)d_in[12];
    const float* w_ih_l1b = (const float*)d_in[13];
    const float* w_hh_l1b = (const float*)d_in[14];
    const float* b_ih_l1b = (const float*)d_in[15];
    const float* b_hh_l1b = (const float*)d_in[16];
    const float* fc_w     = (const float*)d_in[17];
    const float* fc_b     = (const float*)d_in[18];
    const float* upw_w    = (const float*)d_in[19];
    const float* upw_b    = (const float*)d_in[20];

    // workspace layout (floats)
    float* gxb    = (float*)d_ws;                       // 256*64*2304
    float* buf2   = gxb  + (size_t)TT * BB * G6;        // 256*64*768
    float* hbuf   = buf2 + (size_t)TT * BB * DD;        // 2*2*96*64*4 = 98304
    float* logits = hbuf + (size_t)98304;               // 64*256      = 16384
    unsigned* cnt = (unsigned*)(logits + 16384);        // 4 barrier counters

    // zero h ping-pong + logits + counters (contiguous region)
    hipMemsetAsync(hbuf, 0, (size_t)(98304 + 16384) * sizeof(float) + 16, stream);

    // layer 0 input gates
    gemm_gx<<<dim3(18, 128), 256, 0, stream>>>(S, 0, w_ih_l0f, w_ih_l0b,
                                               b_ih_l0f, b_ih_l0b, gxb);
    // layer 0 recurrence -> buf2
    {
        unsigned* c0 = cnt;
        void* args[] = {(void*)&gxb, (void*)&w_hh_l0f, (void*)&w_hh_l0b,
                        (void*)&b_hh_l0f, (void*)&b_hh_l0b, (void*)&hbuf,
                        (void*)&buf2, (void*)&c0};
        hipLaunchCooperativeKernel((const void*)recur2, dim3(192), dim3(256),
                                   args, 0, stream);
    }
    // re-zero h for layer 1 (layer-1 counters are separate, already 0)
    hipMemsetAsync(hbuf, 0, (size_t)98304 * sizeof(float), stream);

    // layer 1 input gates (from buf2)
    gemm_gx<<<dim3(18, 128), 256, 0, stream>>>(buf2, 1, w_ih_l1f, w_ih_l1b,
                                               b_ih_l1f, b_ih_l1b, gxb);
    // layer 1 recurrence -> buf2 (overwrites; gx already materialized)
    {
        unsigned* c1 = cnt + 2;
        void* args[] = {(void*)&gxb, (void*)&w_hh_l1f, (void*)&w_hh_l1b,
                        (void*)&b_hh_l1f, (void*)&b_hh_l1b, (void*)&hbuf,
                        (void*)&buf2, (void*)&c1};
        hipLaunchCooperativeKernel((const void*)recur2, dim3(192), dim3(256),
                                   args, 0, stream);
    }
    // attention logits + pooling
    attn_logits<<<dim3(6, 128), 256, 0, stream>>>(buf2, fc_w, fc_b, upw_w, logits);
    softmax_pool<<<64, 256, 0, stream>>>(logits, upw_b, buf2, (float*)d_out);
}